// Round 9
// baseline (198.189 us; speedup 1.0000x reference)
//
#include <hip/hip_runtime.h>
#include <hip/hip_bf16.h>
#include <stdint.h>

// Problem constants (GroupedQueryAttention: B=2,S=2048,D=1024,H=16,KVH=4)
#define B_    2
#define S_    2048
#define D_    1024
#define H_    16
#define KVH_  4
#define HD_   64
#define REP_  4
#define BS_   (B_ * S_)        // 4096 tokens
#define KVD_  256
#define QKVS_ 1536             // fused QKV row stride: Q(1024) | K(256) | V(256)
#define NT_   (S_ / 64)        // 32 KV tiles

typedef unsigned short u16;
typedef short s16x8 __attribute__((ext_vector_type(8)));
typedef float f32x4 __attribute__((ext_vector_type(4)));
typedef float f32x16 __attribute__((ext_vector_type(16)));

typedef const __attribute__((address_space(1))) void* gvp;
typedef __attribute__((address_space(3))) void* lvp;

#define MFMA32 __builtin_amdgcn_mfma_f32_32x32x16_bf16

__device__ __forceinline__ u16 f2b(float f) {  // RNE f32->bf16 (finite inputs)
  uint32_t u = __float_as_uint(f);
  u += 0x7fffu + ((u >> 16) & 1u);
  return (u16)(u >> 16);
}

// XOR swizzle for 64-elem-wide bf16 LDS rows (128B = 8 x 16B slots).
__device__ __forceinline__ int swz64(int row, int slot) {
  return slot ^ (row & 7) ^ ((row >> 3) & 7);
}
__device__ __forceinline__ const s16x8* frag64(const u16* base, int row, int slot) {
  return reinterpret_cast<const s16x8*>(base + row * 64 + swz64(row, slot) * 8);
}

// ---------------- f32 -> bf16 conversion, x4 vectorized ----------------
__global__ void cvt_kernel(const float* __restrict__ in, u16* __restrict__ out, int n4) {
  int i = blockIdx.x * blockDim.x + threadIdx.x;
  if (i >= n4) return;
  const float4 v = reinterpret_cast<const float4*>(in)[i];
  uint2 o;
  o.x = (uint32_t)f2b(v.x) | ((uint32_t)f2b(v.y) << 16);
  o.y = (uint32_t)f2b(v.z) | ((uint32_t)f2b(v.w) << 16);
  reinterpret_cast<uint2*>(out)[i] = o;
}

// ---------------- bf16 GEMM, C = A(MxK) * B(NxK)^T (m97 structure) ----------------
template <int OUT_BF16>
__global__ __launch_bounds__(256) void gemm_bt(const u16* __restrict__ A,
                                               const u16* __restrict__ Bw,
                                               void* __restrict__ Cout,
                                               int M, int N, int K) {
  __shared__ u16 As[128 * 32];
  __shared__ u16 Bs[128 * 32];
  const int tid = threadIdx.x;
  const int lane = tid & 63;
  const int wid = tid >> 6;
  const int l16 = lane & 15;
  const int kq = lane >> 4;
  const int bm = blockIdx.y * 128;
  const int bn = blockIdx.x * 128;
  const int wr = (wid >> 1) * 64;
  const int wc = (wid & 1) * 64;

  f32x4 acc[4][4] = {};

  for (int kt = 0; kt < K; kt += 32) {
    __syncthreads();
#pragma unroll
    for (int i = 0; i < 2; ++i) {
      const int e = (i * 256 + tid) * 8;
      const int row = e >> 5;
      const int col = e & 31;
      __builtin_amdgcn_global_load_lds((gvp)(A + (size_t)(bm + row) * K + kt + col),
                                       (lvp)(&As[e]), 16, 0, 0);
      __builtin_amdgcn_global_load_lds((gvp)(Bw + (size_t)(bn + row) * K + kt + col),
                                       (lvp)(&Bs[e]), 16, 0, 0);
    }
    __syncthreads();

    s16x8 af[4], bfr[4];
#pragma unroll
    for (int m = 0; m < 4; ++m)
      af[m] = *reinterpret_cast<const s16x8*>(&As[(wr + m * 16 + l16) * 32 + kq * 8]);
#pragma unroll
    for (int n = 0; n < 4; ++n)
      bfr[n] = *reinterpret_cast<const s16x8*>(&Bs[(wc + n * 16 + l16) * 32 + kq * 8]);
#pragma unroll
    for (int m = 0; m < 4; ++m)
#pragma unroll
      for (int n = 0; n < 4; ++n)
        acc[m][n] = __builtin_amdgcn_mfma_f32_16x16x32_bf16(af[m], bfr[n], acc[m][n], 0, 0, 0);
  }

#pragma unroll
  for (int m = 0; m < 4; ++m) {
    const int row0 = bm + wr + m * 16 + kq * 4;
#pragma unroll
    for (int n = 0; n < 4; ++n) {
      const int col = bn + wc + n * 16 + l16;
#pragma unroll
      for (int r = 0; r < 4; ++r) {
        if (OUT_BF16) {
          ((u16*)Cout)[(size_t)(row0 + r) * N + col] = f2b(acc[m][n][r]);
        } else {
          ((float*)Cout)[(size_t)(row0 + r) * N + col] = acc[m][n][r];
        }
      }
    }
  }
}

// ---------------- flash attention (GQA): 32x32 swapped structure ----------------
// grid (S/32, B*KVH), 256 thr = 4 waves (one head each), 32 q-rows per wave.
// S^T = mfma32(K, Q): lane holds 32 kv-scores of q=lane&31 (2 f32x16); softmax
// fully per-lane (+1 shfl_xor(32)). P -> A-frags via 16 cvt_pk + shfl_xor(32)
// exchange (verified primitives). V staged transposed Vt[d][kv] (scatter,
// verified) -> B-frags via frag64. O = mfma32(P, V): q in regs, d in lanes ->
// coalesced 64B stores. Mask in regs (ballot fast-path). T14 dbuf staging.
__global__ __launch_bounds__(256) void attn_kernel(const u16* __restrict__ QKV,
                                                   const int* __restrict__ mask,
                                                   u16* __restrict__ O) {
  __shared__ u16 Ks[2][64 * 64];   // row-major, slot-swizzled
  __shared__ u16 Vt[2][64 * 64];   // Vt[d][kv], slot-swizzled

  const int tid = threadIdx.x;
  const int lane = tid & 63;
  const int wid = tid >> 6;            // 0..3 = head within group
  const int q32 = lane & 31;           // q row (for S^T cols / O rows-in-regs)
  const int hi = lane >> 5;            // k-half for MFMA frags
  const int hi4 = hi * 4;
  const int bg = blockIdx.y;
  const int b = bg >> 2;
  const int g = bg & 3;
  const int h = g * REP_ + wid;
  const int q0 = blockIdx.x * 32;
  const u16* kv_base = QKV + (size_t)b * S_ * QKVS_ + D_ + g * HD_;  // K cols
  const float Cs = 0.18033688011112042f;   // SCALE * log2(e)

  // staging geometry
  const int vkvr = tid >> 2;           // V: kv row this thread stages
  const int vdc = (tid & 3) * 16;      // 16 d elems (2 x uint4)

  auto kstage = [&](int buf, int kv0) {
#pragma unroll
    for (int i = 0; i < 2; ++i) {
      const int e = (i * 256 + tid) * 8;
      const int row = e >> 6;
      const int slot = (e >> 3) & 7;
      __builtin_amdgcn_global_load_lds(
          (gvp)(kv_base + (size_t)(kv0 + row) * QKVS_ + swz64(row, slot) * 8),
          (lvp)(&Ks[buf][e]), 16, 0, 0);
    }
  };
  auto vload = [&](int kv0, uint4* va) {
    const u16* p = kv_base + (size_t)(kv0 + vkvr) * QKVS_ + KVD_ + vdc;
    va[0] = *reinterpret_cast<const uint4*>(p);
    va[1] = *reinterpret_cast<const uint4*>(p + 8);
  };
  auto vwrite = [&](int buf, const uint4* va) {
    const int sl = vkvr >> 3;
    const int wv = vkvr & 7;
    u16* vt = &Vt[buf][0];
#pragma unroll
    for (int i = 0; i < 2; ++i) {
      const uint32_t vv[4] = {va[i].x, va[i].y, va[i].z, va[i].w};
#pragma unroll
      for (int j = 0; j < 4; ++j) {
        const int d0 = vdc + i * 8 + 2 * j;
        const int d1 = d0 + 1;
        vt[d0 * 64 + swz64(d0, sl) * 8 + wv] = (u16)(vv[j] & 0xffffu);
        vt[d1 * 64 + swz64(d1, sl) * 8 + wv] = (u16)(vv[j] >> 16);
      }
    }
  };

  // Q B-frags: lane q=q32, qf[ks] = Q[q][ks*16 + hi*8 .. +7]
  s16x8 qf[4];
  {
    const u16* qp = QKV + (size_t)(b * S_ + q0 + q32) * QKVS_ + h * HD_ + hi * 8;
#pragma unroll
    for (int ks = 0; ks < 4; ++ks)
      qf[ks] = *reinterpret_cast<const s16x8*>(qp + ks * 16);
  }

  // prologue: stage tile 0 into buf 0
  {
    uint4 v0[2];
    vload(0, v0);
    kstage(0, 0);
    vwrite(0, v0);
  }
  int mcur = mask[b * S_ + lane];

  float m_run = -3.0e38f, l_run = 0.f;
  f32x16 acc[2];
#pragma unroll
  for (int i = 0; i < 16; ++i) { acc[0][i] = 0.f; acc[1][i] = 0.f; }
  int cur = 0;

  for (int t = 0; t < NT_; ++t) {
    __syncthreads();                   // drains vmcnt/lgkm -> buf[cur] ready
    int mnext = 0;
    uint4 vreg[2];
    const bool pfch = (t + 1 < NT_);
    if (pfch) {
      vload((t + 1) * 64, vreg);       // V regs first (T14 issue-early)
      kstage(cur ^ 1, (t + 1) * 64);   // K direct-to-LDS (stays in flight)
      mnext = mask[b * S_ + (t + 1) * 64 + lane];
    }

    const u16* ksb = &Ks[cur][0];
    const u16* vtb = &Vt[cur][0];

    // ---- S^T = K · Q^T (raw scores), kv tiles 0..31 (s0) and 32..63 (s1) ----
    f32x16 s0, s1;
#pragma unroll
    for (int i = 0; i < 16; ++i) { s0[i] = 0.f; s1[i] = 0.f; }
#pragma unroll
    for (int ks = 0; ks < 4; ++ks) {
      const s16x8 kf0 = *frag64(ksb, q32, 2 * ks + hi);
      const s16x8 kf1 = *frag64(ksb, 32 + q32, 2 * ks + hi);
      s0 = MFMA32(kf0, qf[ks], s0, 0, 0, 0);
      s1 = MFMA32(kf1, qf[ks], s1, 0, 0, 0);
    }

    // ---- mask (fast path: all valid -> skip) ----
    if (!__all(mcur != 0)) {
      const float mv = (mcur != 0) ? 0.f : -3.0e38f;
#pragma unroll
      for (int r = 0; r < 16; ++r) {
        const int kvi = (r & 3) + 8 * (r >> 2) + hi4;
        s0[r] += __shfl(mv, kvi);
        s1[r] += __shfl(mv, 32 + kvi);
      }
    }

    // ---- per-lane row max (q = lane&31; partner lane holds other 32 kv) ----
    float tm = fmaxf(s0[0], s1[0]);
#pragma unroll
    for (int i = 1; i < 16; ++i) tm = fmaxf(tm, fmaxf(s0[i], s1[i]));
    tm = fmaxf(tm, __shfl_xor(tm, 32));

    // ---- defer-rescale (T13), raw domain: 44 raw ~= 8 exp2-units ----
    if (!__all(tm <= m_run + 44.0f)) {
      const float mnew = fmaxf(m_run, tm);
      const float fac = exp2f((m_run - mnew) * Cs);
      m_run = mnew;
      l_run *= fac;
#pragma unroll
      for (int r = 0; r < 16; ++r) {
        const float fr = __shfl(fac, (r & 3) + 8 * (r >> 2) + hi4);
        acc[0][r] *= fr;
        acc[1][r] *= fr;
      }
    }

    // ---- exp2 + sum ----
    float rs = 0.f;
    const float mneg = -m_run * Cs;
#pragma unroll
    for (int i = 0; i < 16; ++i) {
      const float p0 = exp2f(fmaf(s0[i], Cs, mneg));
      const float p1 = exp2f(fmaf(s1[i], Cs, mneg));
      s0[i] = p0;
      s1[i] = p1;
      rs += p0 + p1;
    }
    rs += __shfl_xor(rs, 32);
    l_run += rs;

    // ---- P -> bf16 pairs: pk[i] = (P[q][kv16(2i)], P[q][kv16(2i+1)]) ----
    uint32_t pk0[8], pk1[8];
#pragma unroll
    for (int rp = 0; rp < 8; ++rp) {
      asm("v_cvt_pk_bf16_f32 %0, %1, %2" : "=v"(pk0[rp]) : "v"(s0[2 * rp]), "v"(s0[2 * rp + 1]));
      asm("v_cvt_pk_bf16_f32 %0, %1, %2" : "=v"(pk1[rp]) : "v"(s1[2 * rp]), "v"(s1[2 * rp + 1]));
    }
    // ---- exchange across lane^32 (verified shfl) into A-frags pf0..pf3 ----
    // pf word w = P pair(kv = slice*16 + hi*8 + 2w, +1). Per quad (x0..x3):
    // w0 = hi ? partner(x2) : x0;  w1 = hi ? partner(x3) : x1;
    // w2 = hi ? x2 : partner(x0);  w3 = hi ? x3 : partner(x1).
    union Up { uint32_t u[4]; s16x8 v; } pf[4];
#pragma unroll
    for (int c = 0; c < 4; ++c) {
      const uint32_t x0 = (c < 2) ? pk0[4 * c] : pk1[4 * (c - 2)];
      const uint32_t x1 = (c < 2) ? pk0[4 * c + 1] : pk1[4 * (c - 2) + 1];
      const uint32_t x2 = (c < 2) ? pk0[4 * c + 2] : pk1[4 * (c - 2) + 2];
      const uint32_t x3 = (c < 2) ? pk0[4 * c + 3] : pk1[4 * (c - 2) + 3];
      const uint32_t p0 = __shfl_xor(x0, 32);
      const uint32_t p1 = __shfl_xor(x1, 32);
      const uint32_t p2 = __shfl_xor(x2, 32);
      const uint32_t p3 = __shfl_xor(x3, 32);
      pf[c].u[0] = hi ? p2 : x0;
      pf[c].u[1] = hi ? p3 : x1;
      pf[c].u[2] = hi ? x2 : p0;
      pf[c].u[3] = hi ? x3 : p1;
    }

    // ---- PV: acc[m] += P · V; V B-frag = Vt row d, kv slice (frag64) ----
#pragma unroll
    for (int m = 0; m < 2; ++m) {
      const int drow = m * 32 + q32;
#pragma unroll
      for (int ks = 0; ks < 4; ++ks) {
        const s16x8 vf = *frag64(vtb, drow, 2 * ks + hi);
        acc[m] = MFMA32(pf[ks].v, vf, acc[m], 0, 0, 0);
      }
    }

    // ---- late STAGE-WRITE (T14): V regs into buf^1 ----
    if (pfch) vwrite(cur ^ 1, vreg);
    mcur = mnext;
    cur ^= 1;
  }

  // ---- epilogue: normalize + store; acc rows=q in regs, cols=d in lanes ----
  const float rl = 1.0f / l_run;
  u16* ob = O + (size_t)(b * S_ + q0) * D_ + h * HD_ + q32;  // q32 = d col here
#pragma unroll
  for (int r = 0; r < 16; ++r) {
    const int rowq = (r & 3) + 8 * (r >> 2) + hi4;
    const float rlr = __shfl(rl, rowq);
    ob[(size_t)rowq * D_] = f2b(acc[0][r] * rlr);
    ob[(size_t)rowq * D_ + 32] = f2b(acc[1][r] * rlr);
  }
}

// ---------------- launch ----------------
extern "C" void kernel_launch(void* const* d_in, const int* in_sizes, int n_in,
                              void* d_out, int out_size, void* d_ws, size_t ws_size,
                              hipStream_t stream) {
  const float* x = (const float*)d_in[0];
  const int* mask = (const int*)d_in[1];
  const float* Wq = (const float*)d_in[2];
  const float* Wk = (const float*)d_in[3];
  const float* Wv = (const float*)d_in[4];
  const float* Wo = (const float*)d_in[5];

  char* w = (char*)d_ws;
  u16* xb = (u16*)w;    w += (size_t)BS_ * D_ * 2;
  u16* Wqkvb = (u16*)w; w += (size_t)QKVS_ * D_ * 2;  // Wq(1024)|Wk(256)|Wv(256) rows
  u16* Wob = (u16*)w;   w += (size_t)D_ * D_ * 2;
  u16* QKVw = (u16*)w;  w += (size_t)BS_ * QKVS_ * 2; // [token][ Q | K | V ]
  u16* AOw = (u16*)w;   w += (size_t)BS_ * D_ * 2;

  auto cvt = [&](const float* src, u16* dst, int n) {
    int n4 = n / 4;
    cvt_kernel<<<dim3((n4 + 255) / 256), dim3(256), 0, stream>>>(src, dst, n4);
  };
  cvt(x, xb, BS_ * D_);
  cvt(Wq, Wqkvb, D_ * D_);
  cvt(Wk, Wqkvb + (size_t)D_ * D_, KVD_ * D_);
  cvt(Wv, Wqkvb + (size_t)(D_ + KVD_) * D_, KVD_ * D_);
  cvt(Wo, Wob, D_ * D_);

  // fused QKV projection: (4096 x 1536) = xb * Wqkv^T
  gemm_bt<1><<<dim3(QKVS_ / 128, BS_ / 128), dim3(256), 0, stream>>>(xb, Wqkvb, QKVw, BS_, QKVS_, D_);
  // attention: (S/32, B*KVH) blocks of 4 waves, 32 q-rows/wave, 32x32 MFMA
  attn_kernel<<<dim3(S_ / 32, B_ * KVH_), dim3(256), 0, stream>>>(QKVw, mask, AOw);
  // output projection -> fp32 d_out
  gemm_bt<0><<<dim3(D_ / 128, BS_ / 128), dim3(256), 0, stream>>>(AOw, Wob, (float*)d_out, BS_, D_, D_);
}

// Round 10
// 159.870 us; speedup vs baseline: 1.2397x; 1.2397x over previous
//
#include <hip/hip_runtime.h>
#include <hip/hip_bf16.h>
#include <stdint.h>

// Problem constants (GroupedQueryAttention: B=2,S=2048,D=1024,H=16,KVH=4)
#define B_    2
#define S_    2048
#define D_    1024
#define H_    16
#define KVH_  4
#define HD_   64
#define REP_  4
#define BS_   (B_ * S_)        // 4096 tokens
#define KVD_  256
#define QKVS_ 1536             // fused QKV row stride: Q(1024) | K(256) | V(256)
#define NT_   (S_ / 64)        // 32 KV tiles

typedef unsigned short u16;
typedef short s16x8 __attribute__((ext_vector_type(8)));
typedef float f32x4 __attribute__((ext_vector_type(4)));

typedef const __attribute__((address_space(1))) void* gvp;
typedef __attribute__((address_space(3))) void* lvp;

__device__ __forceinline__ u16 f2b(float f) {  // RNE f32->bf16 (finite inputs)
  uint32_t u = __float_as_uint(f);
  u += 0x7fffu + ((u >> 16) & 1u);
  return (u16)(u >> 16);
}

// XOR swizzle for 64-elem-wide bf16 LDS rows (128B = 8 x 16B slots).
__device__ __forceinline__ int swz64(int row, int slot) {
  return slot ^ (row & 7) ^ ((row >> 3) & 7);
}
__device__ __forceinline__ const s16x8* frag64(const u16* base, int row, int slot) {
  return reinterpret_cast<const s16x8*>(base + row * 64 + swz64(row, slot) * 8);
}

// ---------------- fused f32 -> bf16 conversion over 5 segments ----------------
// dst segments are CONTIGUOUS in ws: xb | Wq | Wk | Wv | Wo.
#define N0_ (BS_ * D_ / 4)
#define N1_ (D_ * D_ / 4)
#define N2_ (KVD_ * D_ / 4)
__global__ void cvt5_kernel(const float* __restrict__ s0, const float* __restrict__ s1,
                            const float* __restrict__ s2, const float* __restrict__ s3,
                            const float* __restrict__ s4, u16* __restrict__ dst, int n4tot) {
  for (int i = blockIdx.x * blockDim.x + threadIdx.x; i < n4tot;
       i += gridDim.x * blockDim.x) {
    const float* src;
    int j = i;
    if (j < N0_) src = s0;
    else if ((j -= N0_) < N1_) src = s1;
    else if ((j -= N1_) < N2_) src = s2;
    else if ((j -= N2_) < N2_) src = s3;
    else { j -= N2_; src = s4; }
    const float4 v = reinterpret_cast<const float4*>(src)[j];
    uint2 o;
    o.x = (uint32_t)f2b(v.x) | ((uint32_t)f2b(v.y) << 16);
    o.y = (uint32_t)f2b(v.z) | ((uint32_t)f2b(v.w) << 16);
    reinterpret_cast<uint2*>(dst)[i] = o;
  }
}

// ---------------- bf16 GEMM, C = A(MxK) * B(NxK)^T (m97 structure) ----------------
template <int OUT_BF16>
__global__ __launch_bounds__(256) void gemm_bt(const u16* __restrict__ A,
                                               const u16* __restrict__ Bw,
                                               void* __restrict__ Cout,
                                               int M, int N, int K) {
  __shared__ u16 As[128 * 32];
  __shared__ u16 Bs[128 * 32];
  const int tid = threadIdx.x;
  const int lane = tid & 63;
  const int wid = tid >> 6;
  const int l16 = lane & 15;
  const int kq = lane >> 4;
  const int bm = blockIdx.y * 128;
  const int bn = blockIdx.x * 128;
  const int wr = (wid >> 1) * 64;
  const int wc = (wid & 1) * 64;

  f32x4 acc[4][4] = {};

  for (int kt = 0; kt < K; kt += 32) {
    __syncthreads();
#pragma unroll
    for (int i = 0; i < 2; ++i) {
      const int e = (i * 256 + tid) * 8;
      const int row = e >> 5;
      const int col = e & 31;
      __builtin_amdgcn_global_load_lds((gvp)(A + (size_t)(bm + row) * K + kt + col),
                                       (lvp)(&As[e]), 16, 0, 0);
      __builtin_amdgcn_global_load_lds((gvp)(Bw + (size_t)(bn + row) * K + kt + col),
                                       (lvp)(&Bs[e]), 16, 0, 0);
    }
    __syncthreads();

    s16x8 af[4], bfr[4];
#pragma unroll
    for (int m = 0; m < 4; ++m)
      af[m] = *reinterpret_cast<const s16x8*>(&As[(wr + m * 16 + l16) * 32 + kq * 8]);
#pragma unroll
    for (int n = 0; n < 4; ++n)
      bfr[n] = *reinterpret_cast<const s16x8*>(&Bs[(wc + n * 16 + l16) * 32 + kq * 8]);
#pragma unroll
    for (int m = 0; m < 4; ++m)
#pragma unroll
      for (int n = 0; n < 4; ++n)
        acc[m][n] = __builtin_amdgcn_mfma_f32_16x16x32_bf16(af[m], bfr[n], acc[m][n], 0, 0, 0);
  }

#pragma unroll
  for (int m = 0; m < 4; ++m) {
    const int row0 = bm + wr + m * 16 + kq * 4;
#pragma unroll
    for (int n = 0; n < 4; ++n) {
      const int col = bn + wc + n * 16 + l16;
#pragma unroll
      for (int r = 0; r < 4; ++r) {
        if (OUT_BF16) {
          ((u16*)Cout)[(size_t)(row0 + r) * N + col] = f2b(acc[m][n][r]);
        } else {
          ((float*)Cout)[(size_t)(row0 + r) * N + col] = acc[m][n][r];
        }
      }
    }
  }
}

// ---------------- V transpose: QKV V-part -> VT[(b*4+g)*64 + d][s] ----------------
__global__ __launch_bounds__(256) void vtrans_kernel(const u16* __restrict__ QKV,
                                                     u16* __restrict__ VT) {
  __shared__ u16 T[64][72];            // row stride 144B = 9x16B (aligned, bank-spread)
  const int tid = threadIdx.x;
  const int s0 = blockIdx.x * 64;
  const int bg = blockIdx.y;
  const int b = bg >> 2;
  const int g = bg & 3;
  const int r = tid >> 2;              // token row within tile
  const int c0 = (tid & 3) * 16;       // d col base
  const u16* src = QKV + (size_t)(b * S_ + s0 + r) * QKVS_ + D_ + KVD_ + g * HD_ + c0;
  const uint4 a = reinterpret_cast<const uint4*>(src)[0];
  const uint4 bq = reinterpret_cast<const uint4*>(src)[1];
  *reinterpret_cast<uint4*>(&T[r][c0]) = a;
  *reinterpret_cast<uint4*>(&T[r][c0 + 8]) = bq;
  __syncthreads();
  const int d = tid >> 2;              // d row of output
  u16 tmp[16];
#pragma unroll
  for (int j = 0; j < 16; ++j) tmp[j] = T[c0 + j][d];
  u16* dst = VT + ((size_t)bg * 64 + d) * S_ + s0 + c0;
  *reinterpret_cast<uint4*>(dst) = *reinterpret_cast<const uint4*>(&tmp[0]);
  *reinterpret_cast<uint4*>(dst + 8) = *reinterpret_cast<const uint4*>(&tmp[8]);
}

// ---------------- flash attention (GQA): swapped-QK^T, 32 q-rows/wave ----------------
// Round-7 verified structure; V now staged DIRECTLY via global_load_lds from
// pre-transposed VT (like K) -- no reg round-trip, no scattered ds_writes.
__global__ __launch_bounds__(256) void attn_kernel(const u16* __restrict__ QKV,
                                                   const u16* __restrict__ VT,
                                                   const int* __restrict__ mask,
                                                   u16* __restrict__ O) {
  __shared__ u16 Ks[2][64 * 64];
  __shared__ u16 Vt[2][64 * 64];       // Vt[d][kv], slot-swizzled
  __shared__ float smask[2][64];

  const int tid = threadIdx.x;
  const int lane = tid & 63;
  const int wid = tid >> 6;            // 0..3 = head within group
  const int l16 = lane & 15;
  const int kq = lane >> 4;            // 0..3
  const int bg = blockIdx.y;
  const int b = bg >> 2;               // / KVH
  const int g = bg & 3;
  const int h = g * REP_ + wid;
  const int q0 = blockIdx.x * 32;
  const u16* kv_base = QKV + (size_t)b * S_ * QKVS_ + D_ + g * HD_;  // K cols
  const u16* vt_base = VT + (size_t)bg * 64 * S_;                     // V^T rows

  auto kstage = [&](int buf, int kv0) {
#pragma unroll
    for (int i = 0; i < 2; ++i) {
      const int e = (i * 256 + tid) * 8;
      const int row = e >> 6;
      const int slot = (e >> 3) & 7;
      __builtin_amdgcn_global_load_lds(
          (gvp)(kv_base + (size_t)(kv0 + row) * QKVS_ + swz64(row, slot) * 8),
          (lvp)(&Ks[buf][e]), 16, 0, 0);
    }
  };
  auto vstage = [&](int buf, int kv0) {
#pragma unroll
    for (int i = 0; i < 2; ++i) {
      const int e = (i * 256 + tid) * 8;
      const int row = e >> 6;          // d
      const int slot = (e >> 3) & 7;
      __builtin_amdgcn_global_load_lds(
          (gvp)(vt_base + (size_t)row * S_ + kv0 + swz64(row, slot) * 8),
          (lvp)(&Vt[buf][e]), 16, 0, 0);
    }
  };

  // Q B-frags: qf[g2][c] = Q[q0+g2*16+l16][c*32+kq*8..], group g2 in {0,1}
  s16x8 qf[2][2];
#pragma unroll
  for (int g2 = 0; g2 < 2; ++g2) {
    const u16* qp = QKV + (size_t)(b * S_ + q0 + g2 * 16 + l16) * QKVS_ + h * HD_ + kq * 8;
    qf[g2][0] = *reinterpret_cast<const s16x8*>(qp);
    qf[g2][1] = *reinterpret_cast<const s16x8*>(qp + 32);
  }

  // prologue: stage tile 0 into buf 0
  kstage(0, 0);
  vstage(0, 0);
  {
    int mr = 0;
    if (tid < 64) mr = mask[b * S_ + tid];
    if (tid < 64) smask[0][tid] = mr ? 0.f : -1e30f;
  }

  float m_run[2] = {-1e30f, -1e30f}, l_run[2] = {0.f, 0.f};
  f32x4 acc[2][4] = {};                // O^T per group: row d=m*16+kq*4+r, col q=l16
  const float Cs = 0.18033688011112042f;  // SCALE * log2(e)
  int cur = 0;

  for (int t = 0; t < NT_; ++t) {
    __syncthreads();                   // buf[cur] ready; buf[cur^1] free
    const bool pfch = (t + 1 < NT_);
    int mreg = 0;
    if (pfch) {
      kstage(cur ^ 1, (t + 1) * 64);   // direct-to-LDS, stays in flight
      vstage(cur ^ 1, (t + 1) * 64);
      if (tid < 64) mreg = mask[b * S_ + (t + 1) * 64 + tid];
    }

    const u16* ks = &Ks[cur][0];
    const u16* vt = &Vt[cur][0];
    const float* sm = &smask[cur][0];

    // S^T = K·Q^T for both q-groups; K frag read shared
    f32x4 sc[2][4];
#pragma unroll
    for (int n = 0; n < 4; ++n) {
      f32x4 s0 = {0.f, 0.f, 0.f, 0.f};
      f32x4 s1 = {0.f, 0.f, 0.f, 0.f};
#pragma unroll
      for (int c = 0; c < 2; ++c) {
        const s16x8 kf = *frag64(ks, n * 16 + l16, c * 4 + kq);
        s0 = __builtin_amdgcn_mfma_f32_16x16x32_bf16(kf, qf[0][c], s0, 0, 0, 0);
        s1 = __builtin_amdgcn_mfma_f32_16x16x32_bf16(kf, qf[1][c], s1, 0, 0, 0);
      }
      sc[0][n] = s0;
      sc[1][n] = s1;
    }

    // mask values shared by both groups (depend only on kv row)
    f32x4 mk[4];
#pragma unroll
    for (int n = 0; n < 4; ++n)
      mk[n] = *reinterpret_cast<const f32x4*>(&sm[n * 16 + kq * 4]);

    union { uint32_t u[4]; s16x8 v; } pf[2][2];
#pragma unroll
    for (int g2 = 0; g2 < 2; ++g2) {
      float tm = -1e30f;
#pragma unroll
      for (int n = 0; n < 4; ++n)
#pragma unroll
        for (int r = 0; r < 4; ++r) {
          sc[g2][n][r] = sc[g2][n][r] * Cs + mk[n][r];
          tm = fmaxf(tm, sc[g2][n][r]);
        }
      tm = fmaxf(tm, __shfl_xor(tm, 16));
      tm = fmaxf(tm, __shfl_xor(tm, 32));

      // defer-rescale (T13)
      if (!__all(tm <= m_run[g2] + 8.0f)) {
        const float mnew = fmaxf(m_run[g2], tm);
        const float fac = exp2f(m_run[g2] - mnew);
        m_run[g2] = mnew;
        l_run[g2] *= fac;
#pragma unroll
        for (int m = 0; m < 4; ++m)
#pragma unroll
          for (int r = 0; r < 4; ++r) acc[g2][m][r] *= fac;
      }

      float rs = 0.f;
#pragma unroll
      for (int n = 0; n < 4; ++n)
#pragma unroll
        for (int r = 0; r < 4; ++r) {
          const float p = exp2f(sc[g2][n][r] - m_run[g2]);
          sc[g2][n][r] = p;
          rs += p;
        }
      rs += __shfl_xor(rs, 16);
      rs += __shfl_xor(rs, 32);
      l_run[g2] += rs;

      // pack P to bf16 pairs
      uint32_t pk[4][2];
#pragma unroll
      for (int n = 0; n < 4; ++n) {
        asm("v_cvt_pk_bf16_f32 %0, %1, %2" : "=v"(pk[n][0]) : "v"(sc[g2][n][0]), "v"(sc[g2][n][1]));
        asm("v_cvt_pk_bf16_f32 %0, %1, %2" : "=v"(pk[n][1]) : "v"(sc[g2][n][2]), "v"(sc[g2][n][3]));
      }
      // exchange: frag c word w <- pk[2c+(kq>>1)][w&1] of lane ((kq&1)*2+(w>>1))*16+l16
      const int srcA = ((kq & 1) * 2) * 16 + l16;
      const int srcB = srcA + 16;
#pragma unroll
      for (int c = 0; c < 2; ++c)
#pragma unroll
        for (int w = 0; w < 4; ++w) {
          const int src = (w < 2) ? srcA : srcB;
          const uint32_t lo = __shfl(pk[2 * c][w & 1], src);
          const uint32_t hi = __shfl(pk[2 * c + 1][w & 1], src);
          pf[g2][c].u[w] = (kq & 2) ? hi : lo;
        }
    }

    // O^T += V^T·P^T; V frag read shared by both groups
#pragma unroll
    for (int m = 0; m < 4; ++m) {
      const s16x8 vf0 = *frag64(vt, m * 16 + l16, kq);
      const s16x8 vf1 = *frag64(vt, m * 16 + l16, 4 + kq);
      acc[0][m] = __builtin_amdgcn_mfma_f32_16x16x32_bf16(vf0, pf[0][0].v, acc[0][m], 0, 0, 0);
      acc[0][m] = __builtin_amdgcn_mfma_f32_16x16x32_bf16(vf1, pf[0][1].v, acc[0][m], 0, 0, 0);
      acc[1][m] = __builtin_amdgcn_mfma_f32_16x16x32_bf16(vf0, pf[1][0].v, acc[1][m], 0, 0, 0);
      acc[1][m] = __builtin_amdgcn_mfma_f32_16x16x32_bf16(vf1, pf[1][1].v, acc[1][m], 0, 0, 0);
    }

    // late: mask into buf^1 smask
    if (pfch && tid < 64) smask[cur ^ 1][tid] = mreg ? 0.f : -1e30f;
    cur ^= 1;
  }

  // normalize + store O^T -> O (bf16, token-major [BS][D])
#pragma unroll
  for (int g2 = 0; g2 < 2; ++g2) {
    const float rl = 1.0f / l_run[g2];
    u16* op = O + (size_t)(b * S_ + q0 + g2 * 16 + l16) * D_ + h * HD_ + kq * 4;
#pragma unroll
    for (int m = 0; m < 4; ++m) {
      uint2 o;
      o.x = (uint32_t)f2b(acc[g2][m][0] * rl) | ((uint32_t)f2b(acc[g2][m][1] * rl) << 16);
      o.y = (uint32_t)f2b(acc[g2][m][2] * rl) | ((uint32_t)f2b(acc[g2][m][3] * rl) << 16);
      *reinterpret_cast<uint2*>(op + m * 16) = o;
    }
  }
}

// ---------------- launch ----------------
extern "C" void kernel_launch(void* const* d_in, const int* in_sizes, int n_in,
                              void* d_out, int out_size, void* d_ws, size_t ws_size,
                              hipStream_t stream) {
  const float* x = (const float*)d_in[0];
  const int* mask = (const int*)d_in[1];
  const float* Wq = (const float*)d_in[2];
  const float* Wk = (const float*)d_in[3];
  const float* Wv = (const float*)d_in[4];
  const float* Wo = (const float*)d_in[5];

  char* w = (char*)d_ws;
  u16* xb = (u16*)w;    w += (size_t)BS_ * D_ * 2;     // | contiguous cvt dst
  u16* Wqkvb = (u16*)w; w += (size_t)QKVS_ * D_ * 2;   // | Wq|Wk|Wv rows
  u16* Wob = (u16*)w;   w += (size_t)D_ * D_ * 2;      // |
  u16* QKVw = (u16*)w;  w += (size_t)BS_ * QKVS_ * 2;  // [token][ Q | K | V ]
  u16* VTw = (u16*)w;   w += (size_t)B_ * KVH_ * HD_ * S_ * 2;  // [(b,g)][d][s]
  u16* AOw = (u16*)w;   w += (size_t)BS_ * D_ * 2;

  // fused f32->bf16 of x + all weights (dst contiguous from xb)
  const int n4tot = (BS_ * D_ + QKVS_ * D_ + D_ * D_) / 4;
  cvt5_kernel<<<dim3(2048), dim3(256), 0, stream>>>(x, Wq, Wk, Wv, Wo, xb, n4tot);

  // fused QKV projection: (4096 x 1536) = xb * Wqkv^T
  gemm_bt<1><<<dim3(QKVS_ / 128, BS_ / 128), dim3(256), 0, stream>>>(xb, Wqkvb, QKVw, BS_, QKVS_, D_);
  // transpose V for direct LDS staging in attention
  vtrans_kernel<<<dim3(S_ / 64, B_ * KVH_), dim3(256), 0, stream>>>(QKVw, VTw);
  // attention: (S/32, B*KVH) blocks of 4 waves, 32 q-rows/wave
  attn_kernel<<<dim3(S_ / 32, B_ * KVH_), dim3(256), 0, stream>>>(QKVw, VTw, mask, AOw);
  // output projection -> fp32 d_out
  gemm_bt<0><<<dim3(D_ / 128, BS_ / 128), dim3(256), 0, stream>>>(AOw, Wob, (float*)d_out, BS_, D_, D_);
}